// Round 1
// baseline (20630.351 us; speedup 1.0000x reference)
//
#include <hip/hip_runtime.h>

#define TRAJ 4
#define BATCH 256
#define DIM 256
#define HID 1024
#define NT 50
#define NSAMP (TRAJ*BATCH)   // 1024
#define MB 16                // samples per block
#define NBLK (NSAMP/MB)      // 64
#define NTHR 512             // 8 waves

// swizzled-weight offsets in d_ws (ushort elements)
#define W1OFF 0
#define W2OFF (DIM*HID)              // 262144
#define W3OFF (W2OFF + HID*HID)      // 1310720
#define WTOT  (W3OFF + HID*DIM)      // 1572864 elems = 3 MiB

typedef __bf16 bf16x8 __attribute__((ext_vector_type(8)));
typedef float  f32x4  __attribute__((ext_vector_type(4)));
typedef unsigned int uint4v __attribute__((ext_vector_type(4)));

__device__ __forceinline__ unsigned short f2bf(float x) {
    unsigned int b = __float_as_uint(x);
    b += 0x7fffu + ((b >> 16) & 1u);   // round-to-nearest-even
    return (unsigned short)(b >> 16);
}

__device__ __forceinline__ float ftanh(float x) {
    // tanh(x) = 1 - 2/(exp(2x)+1); exp overflow -> 1, underflow -> -1 (correct limits)
    float e = __expf(2.0f * x);
    return 1.0f - 2.0f * __builtin_amdgcn_rcpf(e + 1.0f);
}

__device__ __forceinline__ f32x4 mfma16(uint4v a, uint4v b, f32x4 c) {
    return __builtin_amdgcn_mfma_f32_16x16x32_bf16(
        __builtin_bit_cast(bf16x8, a), __builtin_bit_cast(bf16x8, b), c, 0, 0, 0);
}

// ---------------------------------------------------------------------------
// Prep: swizzle f32 weights into bf16 MFMA B-fragment order in d_ws.
// Fragment (ct, ks): 64 lanes x 8 bf16; element j of lane l =
//   W[ks*32 + (l>>4)*8 + j][ct*16 + (l&15)]
// ---------------------------------------------------------------------------
__global__ void prep_kernel(const float* __restrict__ W1,
                            const float* __restrict__ W2,
                            const float* __restrict__ W3,
                            unsigned short* __restrict__ ws) {
    int bid = blockIdx.x;
    int lane = threadIdx.x;
    const float* W;
    int ncol;
    unsigned short* dst;
    int ct, ks;
    if (bid < 512) {                       // W1: [256][1024], 64 ct x 8 ks
        W = W1; ncol = 1024; ct = bid >> 3; ks = bid & 7;
        dst = ws + W1OFF + ((size_t)bid * 64 + lane) * 8;
    } else if (bid < 2560) {               // W2: [1024][1024], 64 ct x 32 ks
        int b = bid - 512;
        W = W2; ncol = 1024; ct = b >> 5; ks = b & 31;
        dst = ws + W2OFF + ((size_t)b * 64 + lane) * 8;
    } else {                               // W3: [1024][256], 16 ct x 32 ks
        int b = bid - 2560;
        W = W3; ncol = 256; ct = b >> 5; ks = b & 31;
        dst = ws + W3OFF + ((size_t)b * 64 + lane) * 8;
    }
    int col = ct * 16 + (lane & 15);
    int k0  = ks * 32 + (lane >> 4) * 8;
    unsigned short v[8];
#pragma unroll
    for (int j = 0; j < 8; ++j)
        v[j] = f2bf(W[(k0 + j) * ncol + col]);
    *(uint4v*)dst = *(const uint4v*)v;
}

// ---------------------------------------------------------------------------
// Main: persistent per-sample-block RK4 integrator. 64 blocks x 16 samples.
// 8 waves: each owns 128 H-cols (layers 1,2) and 32 D-cols (layer 3 / y).
// y + RK4 accumulator live in f32 registers; activations bf16 in LDS.
// ---------------------------------------------------------------------------
__global__ __launch_bounds__(NTHR, 2) void ode_main(
        const float* __restrict__ y0g, const float* __restrict__ ts,
        const float* __restrict__ b1g, const float* __restrict__ b2g,
        const float* __restrict__ b3g,
        const unsigned short* __restrict__ wsw, float* __restrict__ out) {

    __shared__ __align__(16) unsigned short ys[MB][DIM + 8];   // stage input, bf16
    __shared__ __align__(16) unsigned short h1[MB][HID + 8];
    __shared__ __align__(16) unsigned short h2[MB][HID + 8];

    const int tid  = threadIdx.x;
    const int wave = tid >> 6;
    const int lane = tid & 63;
    const int lr   = lane & 15;     // tile col (and A-row)
    const int lg   = lane >> 4;     // lane group: C rows lg*4..lg*4+3, A k-chunk
    const int s0   = blockIdx.x * MB;
    const int hc0  = wave * 128;    // this wave's H-column base (layers 1,2)
    const int dc0  = wave * 32;     // this wave's D-column base (layer 3)

    // biases, preloaded once
    float bias1[8], bias2[8], bias3[2];
#pragma unroll
    for (int t = 0; t < 8; ++t) {
        bias1[t] = b1g[hc0 + t * 16 + lr];
        bias2[t] = b2g[hc0 + t * 16 + lr];
    }
    bias3[0] = b3g[dc0 + lr];
    bias3[1] = b3g[dc0 + 16 + lr];

    // init: y registers (C-frag positions), seed ys LDS, write out[t=0]
    float yreg[2][4];
#pragma unroll
    for (int t = 0; t < 2; ++t)
#pragma unroll
        for (int j = 0; j < 4; ++j) {
            int row = lg * 4 + j, col = dc0 + t * 16 + lr;
            float v = y0g[(s0 + row) * DIM + col];
            yreg[t][j] = v;
            ys[row][col] = f2bf(v);
            out[((s0 + row) * NT + 0) * DIM + col] = v;
        }
    __syncthreads();

    float acc[2][4];

#pragma unroll 1
    for (int step = 1; step < NT; ++step) {
        float dt = ts[step] - ts[step - 1];
#pragma unroll 1
        for (int stage = 0; stage < 4; ++stage) {
            // ---------------- layer 1: h1 = tanh(ys @ W1 + b1) ----------------
            {
                uint4v a1[8];
#pragma unroll
                for (int ks = 0; ks < 8; ++ks)
                    a1[ks] = *(const uint4v*)&ys[lr][ks * 32 + lg * 8];
#pragma unroll
                for (int ct = 0; ct < 8; ++ct) {
                    f32x4 c = {0.f, 0.f, 0.f, 0.f};
                    const unsigned short* wp =
                        wsw + W1OFF + (size_t)(((hc0 >> 4) + ct) * 8) * 512 + lane * 8;
#pragma unroll
                    for (int ks = 0; ks < 8; ++ks) {
                        uint4v b = *(const uint4v*)(wp + (size_t)ks * 512);
                        c = mfma16(a1[ks], b, c);
                    }
#pragma unroll
                    for (int j = 0; j < 4; ++j)
                        h1[lg * 4 + j][hc0 + ct * 16 + lr] = f2bf(ftanh(c[j] + bias1[ct]));
                }
            }
            __syncthreads();

            // ---------------- layer 2: h2 = tanh(h1 @ W2 + b2) ----------------
            {
                f32x4 c2[8];
#pragma unroll
                for (int ct = 0; ct < 8; ++ct) c2[ct] = (f32x4){0.f, 0.f, 0.f, 0.f};
#pragma unroll
                for (int kc = 0; kc < 4; ++kc) {
                    uint4v a[8];
#pragma unroll
                    for (int ks = 0; ks < 8; ++ks)
                        a[ks] = *(const uint4v*)&h1[lr][kc * 256 + ks * 32 + lg * 8];
#pragma unroll
                    for (int ct = 0; ct < 8; ++ct) {
                        const unsigned short* wp =
                            wsw + W2OFF +
                            (size_t)((((hc0 >> 4) + ct) * 32) + kc * 8) * 512 + lane * 8;
#pragma unroll
                        for (int ks = 0; ks < 8; ++ks) {
                            uint4v b = *(const uint4v*)(wp + (size_t)ks * 512);
                            c2[ct] = mfma16(a[ks], b, c2[ct]);
                        }
                    }
                }
#pragma unroll
                for (int ct = 0; ct < 8; ++ct)
#pragma unroll
                    for (int j = 0; j < 4; ++j)
                        h2[lg * 4 + j][hc0 + ct * 16 + lr] = f2bf(ftanh(c2[ct][j] + bias2[ct]));
            }
            __syncthreads();

            // ---------------- layer 3: k = h2 @ W3 + b3; RK4 update -----------
            {
                f32x4 c3[2];
                c3[0] = (f32x4){0.f, 0.f, 0.f, 0.f};
                c3[1] = (f32x4){0.f, 0.f, 0.f, 0.f};
#pragma unroll
                for (int kc = 0; kc < 4; ++kc) {
                    uint4v a[8];
#pragma unroll
                    for (int ks = 0; ks < 8; ++ks)
                        a[ks] = *(const uint4v*)&h2[lr][kc * 256 + ks * 32 + lg * 8];
#pragma unroll
                    for (int ct = 0; ct < 2; ++ct) {
                        const unsigned short* wp =
                            wsw + W3OFF +
                            (size_t)((((dc0 >> 4) + ct) * 32) + kc * 8) * 512 + lane * 8;
#pragma unroll
                        for (int ks = 0; ks < 8; ++ks) {
                            uint4v b = *(const uint4v*)(wp + (size_t)ks * 512);
                            c3[ct] = mfma16(a[ks], b, c3[ct]);
                        }
                    }
                }

                float accw = (stage == 0 || stage == 3) ? 1.0f : 2.0f;
                float cin  = (stage == 2) ? dt : 0.5f * dt;
#pragma unroll
                for (int t = 0; t < 2; ++t)
#pragma unroll
                    for (int j = 0; j < 4; ++j) {
                        float kv = c3[t][j] + bias3[t];
                        acc[t][j] = (stage == 0) ? kv : acc[t][j] + accw * kv;
                        float ysv;
                        if (stage < 3) {
                            ysv = yreg[t][j] + cin * kv;
                        } else {
                            yreg[t][j] += dt * (1.0f / 6.0f) * acc[t][j];
                            ysv = yreg[t][j];
                            out[((s0 + lg * 4 + j) * NT + step) * DIM + dc0 + t * 16 + lr] = ysv;
                        }
                        ys[lg * 4 + j][dc0 + t * 16 + lr] = f2bf(ysv);
                    }
            }
            __syncthreads();
        }
    }
}

extern "C" void kernel_launch(void* const* d_in, const int* in_sizes, int n_in,
                              void* d_out, int out_size, void* d_ws, size_t ws_size,
                              hipStream_t stream) {
    const float* y0 = (const float*)d_in[0];
    const float* ts = (const float*)d_in[1];
    const float* W1 = (const float*)d_in[2];
    const float* b1 = (const float*)d_in[3];
    const float* W2 = (const float*)d_in[4];
    const float* b2 = (const float*)d_in[5];
    const float* W3 = (const float*)d_in[6];
    const float* b3 = (const float*)d_in[7];
    unsigned short* ws = (unsigned short*)d_ws;
    float* out = (float*)d_out;

    prep_kernel<<<3072, 64, 0, stream>>>(W1, W2, W3, ws);
    ode_main<<<NBLK, NTHR, 0, stream>>>(y0, ts, b1, b2, b3, ws, out);
}